// Round 2
// baseline (1614.776 us; speedup 1.0000x reference)
//
#include <hip/hip_runtime.h>

#define HID 64
#define FEAT 10
#define MAXSEG 8192        // padded csr segment per 256-node bucket
#define NBLK 768           // 3 blocks/CU needed on 256 CUs -> co-resident for VGPR<=170, LDS<=53KB
#define NTHR 256

typedef unsigned short u16;

// ---------- helpers ----------
__device__ __forceinline__ u16 f2bf(float f) {            // fp32 -> bf16 RNE
    unsigned u = __float_as_uint(f);
    unsigned r = (u + 0x7fffu + ((u >> 16) & 1u)) >> 16;
    return (u16)r;
}
__device__ __forceinline__ void bf8_add(float* acc, uint4 u) {
    acc[0] += __uint_as_float(u.x << 16);
    acc[1] += __uint_as_float(u.x & 0xffff0000u);
    acc[2] += __uint_as_float(u.y << 16);
    acc[3] += __uint_as_float(u.y & 0xffff0000u);
    acc[4] += __uint_as_float(u.z << 16);
    acc[5] += __uint_as_float(u.z & 0xffff0000u);
    acc[6] += __uint_as_float(u.w << 16);
    acc[7] += __uint_as_float(u.w & 0xffff0000u);
}

// device-scope grid barrier: one fresh counter per use (memset to 0 pre-launch).
// release: syncthreads (drains block's stores) + threadfence (L2 writeback to coherence point)
// arrive:  device-scope atomicAdd; spin on agent-scope atomic load (never cached stale)
__device__ __forceinline__ void gbar(int* bar, int nblk) {
    __syncthreads();
    if (threadIdx.x == 0) {
        __threadfence();
        atomicAdd(bar, 1);
        while (__hip_atomic_load(bar, __ATOMIC_ACQUIRE, __HIP_MEMORY_SCOPE_AGENT) < nblk)
            __builtin_amdgcn_s_sleep(8);
        __threadfence();
    }
    __syncthreads();
}

union SMem {
    struct { int lh[256]; } h;                                     // hist
    struct { int lds[256]; } sc;                                   // scans
    struct { int cur[256]; } bp;                                   // binpass
    struct { u16 staged[MAXSEG]; int cntL[256]; int padL[256];
             int scanL[256]; int curL[256]; float sdinv[256]; } cb; // csr_build (21KB)
    struct { float sW[FEAT * 64]; float sH[64 * 16]; } m1;          // gather_x+mm1 (6.5KB)
    struct { float sW[64 * 64]; float sH[64 * 65]; } m64;           // mm64 (33KB max)
    struct { float red[32 * 64]; } gb;                              // gsum reduce (8KB)
    struct { float red[256]; float semb[64]; float geoh[64];
             float geo[64]; float hq[128]; } fin;                   // head
};

// ---------- phase bodies ----------

__device__ __forceinline__ void mm64_phase(SMem& sm, const float* h_in, const float* W,
                                           const float* dinv, u16* hwb, int N, int t, int bid) {
    int nch = (N + 63) >> 6;
    for (int g = bid; g < nch; g += NBLK) {
        int node0 = g << 6;
        for (int i = t * 4; i < 4096; i += NTHR * 4)
            *(float4*)(sm.m64.sW + i) = *(const float4*)(W + i);
        for (int i = t; i < 4096; i += NTHR) {
            int r = i >> 6, k = i & 63;
            int node = node0 + r;
            sm.m64.sH[r * 65 + k] = (node < N) ? h_in[(size_t)node * 64 + k] : 0.0f;
        }
        __syncthreads();
        int c0 = (t & 15) * 4;
        int rbase = (t >> 4) * 4;
        float4 a0 = {0,0,0,0}, a1 = {0,0,0,0}, a2 = {0,0,0,0}, a3 = {0,0,0,0};
        for (int k = 0; k < 64; k++) {
            float4 w = *(const float4*)(sm.m64.sW + k * 64 + c0);
            float h0 = sm.m64.sH[(rbase + 0) * 65 + k];
            float h1v = sm.m64.sH[(rbase + 1) * 65 + k];
            float h2 = sm.m64.sH[(rbase + 2) * 65 + k];
            float h3 = sm.m64.sH[(rbase + 3) * 65 + k];
            a0.x += h0 * w.x; a0.y += h0 * w.y; a0.z += h0 * w.z; a0.w += h0 * w.w;
            a1.x += h1v * w.x; a1.y += h1v * w.y; a1.z += h1v * w.z; a1.w += h1v * w.w;
            a2.x += h2 * w.x; a2.y += h2 * w.y; a2.z += h2 * w.z; a2.w += h2 * w.w;
            a3.x += h3 * w.x; a3.y += h3 * w.y; a3.z += h3 * w.z; a3.w += h3 * w.w;
        }
        float4 accs[4] = {a0, a1, a2, a3};
        for (int rr = 0; rr < 4; rr++) {
            int node = node0 + rbase + rr;
            if (node < N) {
                float di = dinv[node];
                float4 v = accs[rr];
                ushort4 o;
                o.x = f2bf(v.x * di); o.y = f2bf(v.y * di);
                o.z = f2bf(v.z * di); o.w = f2bf(v.w * di);
                *(ushort4*)(hwb + (size_t)node * 64 + c0) = o;
            }
        }
        __syncthreads();
    }
}

template <int DO_GSUM>
__device__ __forceinline__ void gather64_phase(SMem& sm, const int* row_start, const int* row_cntp,
                                               const u16* csr2, const u16* hwb, const float* dinv,
                                               const float* b, float* out, float* gsum,
                                               int N, int t, int bid) {
    int nch = (N + 31) >> 5;
    for (int g = bid; g < nch; g += NBLK) {
        int nl = t >> 3;
        int node = (g << 5) + nl;
        int c0 = (t & 7) * 8;
        float acc[8] = {0.f,0.f,0.f,0.f,0.f,0.f,0.f,0.f};
        if (node < N) {
            uint4 sv = *(const uint4*)(hwb + (size_t)node * 64 + c0);
            bf8_add(acc, sv);
            int i0 = row_start[node], iE = i0 + row_cntp[node];
            for (int i = i0; i < iE; i += 8) {
                uint4 ev = *(const uint4*)(csr2 + i);
                int s0 = ev.x & 0xffff, s1 = ev.x >> 16;
                int s2 = ev.y & 0xffff, s3 = ev.y >> 16;
                int s4 = ev.z & 0xffff, s5 = ev.z >> 16;
                int s6 = ev.w & 0xffff, s7 = ev.w >> 16;
                uint4 u0 = *(const uint4*)(hwb + (size_t)s0 * 64 + c0);
                uint4 u1 = *(const uint4*)(hwb + (size_t)s1 * 64 + c0);
                uint4 u2 = *(const uint4*)(hwb + (size_t)s2 * 64 + c0);
                uint4 u3 = *(const uint4*)(hwb + (size_t)s3 * 64 + c0);
                uint4 u4 = *(const uint4*)(hwb + (size_t)s4 * 64 + c0);
                uint4 u5 = *(const uint4*)(hwb + (size_t)s5 * 64 + c0);
                uint4 u6 = *(const uint4*)(hwb + (size_t)s6 * 64 + c0);
                uint4 u7 = *(const uint4*)(hwb + (size_t)s7 * 64 + c0);
                bf8_add(acc, u0); bf8_add(acc, u1); bf8_add(acc, u2); bf8_add(acc, u3);
                bf8_add(acc, u4); bf8_add(acc, u5); bf8_add(acc, u6); bf8_add(acc, u7);
            }
            float di = dinv[node];
            const float4 bb0 = *(const float4*)(b + c0);
            const float4 bb1 = *(const float4*)(b + c0 + 4);
            float4 o0, o1;
            o0.x = fmaxf(acc[0]*di + bb0.x, 0.f); o0.y = fmaxf(acc[1]*di + bb0.y, 0.f);
            o0.z = fmaxf(acc[2]*di + bb0.z, 0.f); o0.w = fmaxf(acc[3]*di + bb0.w, 0.f);
            o1.x = fmaxf(acc[4]*di + bb1.x, 0.f); o1.y = fmaxf(acc[5]*di + bb1.y, 0.f);
            o1.z = fmaxf(acc[6]*di + bb1.z, 0.f); o1.w = fmaxf(acc[7]*di + bb1.w, 0.f);
            *(float4*)(out + (size_t)node * 64 + c0)     = o0;
            *(float4*)(out + (size_t)node * 64 + c0 + 4) = o1;
            acc[0]=o0.x; acc[1]=o0.y; acc[2]=o0.z; acc[3]=o0.w;
            acc[4]=o1.x; acc[5]=o1.y; acc[6]=o1.z; acc[7]=o1.w;
        }
        if (DO_GSUM) {
            __syncthreads();                     // protect red from previous iteration's readers
            #pragma unroll
            for (int j = 0; j < 8; j++) sm.gb.red[nl * 64 + c0 + j] = acc[j];
            __syncthreads();
            if (t < 64) {
                float s = 0.f;
                #pragma unroll 8
                for (int k = 0; k < 32; k++) s += sm.gb.red[k * 64 + t];
                atomicAdd(&gsum[t], s);
            }
        }
    }
}

// ---------- the fused kernel ----------

__global__ __launch_bounds__(NTHR, 3) void fused(
    const float* __restrict__ x, const int* __restrict__ src, const int* __restrict__ dst,
    const int* __restrict__ sheet_idx, const float* __restrict__ sheet_feat,
    const float* __restrict__ W1, const float* __restrict__ b1,
    const float* __restrict__ W2, const float* __restrict__ b2,
    const float* __restrict__ W3, const float* __restrict__ b3,
    const float* __restrict__ gW1, const float* __restrict__ gb1,
    const float* __restrict__ gW2, const float* __restrict__ gb2,
    const float* __restrict__ fW,  const float* __restrict__ fb,
    const float* __restrict__ qW1, const float* __restrict__ qb1,
    const float* __restrict__ qW2, const float* __restrict__ qb2,
    unsigned* tmp, u16* csr2, float* hf, u16* hwb, u16* xp,
    int* row_start, int* row_cntp, float* dinv, float* gsum, int* bars,
    int* cnt2T, int* off2L, int* tot, int* base,
    float* out, int N, int E, int S, int L, int nbuckets, int nchunks) {

    int t = threadIdx.x;
    int bid = blockIdx.x;
    __shared__ __align__(16) SMem sm;

    // ---- P0: chunk histogram ----
    if (bid < nchunks) {
        sm.h.lh[t] = 0;
        __syncthreads();
        int b0 = bid * 4096;
        #pragma unroll
        for (int j = 0; j < 16; j++) {
            int e = b0 + t + j * 256;
            if (e < E) atomicAdd(&sm.h.lh[dst[e] >> 8], 1);
        }
        __syncthreads();
        if (t < nbuckets) cnt2T[t * nchunks + bid] = sm.h.lh[t];
    }
    gbar(bars + 0, NBLK);

    // ---- P1: per-bucket scan over chunks ----
    if (bid < nbuckets) {
        int v = (t < nchunks) ? cnt2T[bid * nchunks + t] : 0;
        sm.sc.lds[t] = v;
        __syncthreads();
        for (int off = 1; off < 256; off <<= 1) {
            int a = sm.sc.lds[t];
            int s2 = (t >= off) ? sm.sc.lds[t - off] : 0;
            __syncthreads();
            sm.sc.lds[t] = a + s2;
            __syncthreads();
        }
        if (t < nchunks) off2L[bid * nchunks + t] = sm.sc.lds[t] - v;
        if (t == 255) tot[bid] = sm.sc.lds[255];
    }
    gbar(bars + 1, NBLK);

    // ---- P2: bucket base scan + sentinels ----
    if (bid == 0) {
        int v = (t < nbuckets) ? tot[t] : 0;
        sm.sc.lds[t] = v;
        __syncthreads();
        for (int off = 1; off < 256; off <<= 1) {
            int a = sm.sc.lds[t];
            int s2 = (t >= off) ? sm.sc.lds[t - off] : 0;
            __syncthreads();
            sm.sc.lds[t] = a + s2;
            __syncthreads();
        }
        if (t < nbuckets) base[t] = sm.sc.lds[t] - v;
    } else if (bid == 1) {
        if (t < 64)      hwb[(size_t)N * 64 + t] = 0;
        else if (t < 80) xp[(size_t)N * 16 + (t - 64)] = 0;
    }
    gbar(bars + 2, NBLK);

    // ---- P3: binning pass ----
    if (bid < nchunks) {
        sm.bp.cur[t] = (t < nbuckets) ? base[t] + off2L[t * nchunks + bid] : 0;
        __syncthreads();
        int b0 = bid * 4096;
        #pragma unroll
        for (int j = 0; j < 16; j++) {
            int e = b0 + t + j * 256;
            if (e < E) {
                int s = src[e], d = dst[e];
                int slot = atomicAdd(&sm.bp.cur[d >> 8], 1);
                tmp[slot] = ((unsigned)(d & 255) << 16) | (unsigned)s;
            }
        }
    }
    gbar(bars + 3, NBLK);

    // ---- P4: csr_build + pad_x ----
    if (bid < nbuckets) {
        sm.cb.cntL[t] = 0;
        for (int i = t; i < MAXSEG; i += NTHR) sm.cb.staged[i] = (u16)N;  // sentinel prefill
        __syncthreads();
        int segBase = base[bid], segLen = tot[bid];
        for (int i = t; i < segLen; i += NTHR)
            atomicAdd(&sm.cb.cntL[tmp[segBase + i] >> 16], 1);
        __syncthreads();
        sm.cb.padL[t] = (sm.cb.cntL[t] + 7) & ~7;
        sm.cb.scanL[t] = sm.cb.padL[t];
        __syncthreads();
        for (int off = 1; off < 256; off <<= 1) {
            int a = sm.cb.scanL[t];
            int s2 = (t >= off) ? sm.cb.scanL[t - off] : 0;
            __syncthreads();
            sm.cb.scanL[t] = a + s2;
            __syncthreads();
        }
        {
            int excl = sm.cb.scanL[t] - sm.cb.padL[t];
            sm.cb.curL[t] = excl;
            float dv = rsqrtf((float)sm.cb.cntL[t] + 1.0f);
            sm.cb.sdinv[t] = dv;
            int node = bid * 256 + t;
            if (node < N) {
                row_start[node] = bid * MAXSEG + excl;
                row_cntp[node]  = sm.cb.padL[t];
                dinv[node]      = dv;
            }
        }
        __syncthreads();
        for (int i = t; i < segLen; i += NTHR) {
            unsigned e = tmp[segBase + i];
            int idx = atomicAdd(&sm.cb.curL[e >> 16], 1);
            sm.cb.staged[idx] = (u16)(e & 0xffffu);
        }
        for (int i = t; i < 256 * 16; i += NTHR) {   // pad_x (independent of staged[])
            int nlc = i >> 4, cch = i & 15;
            int node = bid * 256 + nlc;
            if (node < N)
                xp[(size_t)node * 16 + cch] =
                    (cch < FEAT) ? f2bf(sm.cb.sdinv[nlc] * x[(size_t)node * FEAT + cch]) : (u16)0;
        }
        __syncthreads();
        for (int i = t; i < MAXSEG / 8; i += NTHR)
            ((uint4*)(csr2 + (size_t)bid * MAXSEG))[i] = ((const uint4*)sm.cb.staged)[i];
    }
    gbar(bars + 4, NBLK);

    // ---- P5: gather_x + mm1 (LDS hand-off, no aggx round-trip) ----
    {
        int nch64 = (N + 63) >> 6;
        for (int g = bid; g < nch64; g += NBLK) {
            int node0 = g << 6;
            for (int i = t; i < FEAT * 64; i += NTHR) sm.m1.sW[i] = W1[i];
            if (t < 128) {
                int nl = t >> 1;
                int node = node0 + nl;
                int c0 = (t & 1) * 8;
                float acc[8] = {0.f,0.f,0.f,0.f,0.f,0.f,0.f,0.f};
                if (node < N) {
                    uint4 sv = *(const uint4*)(xp + (size_t)node * 16 + c0);
                    bf8_add(acc, sv);
                    int i0 = row_start[node], iE = i0 + row_cntp[node];
                    for (int i = i0; i < iE; i += 8) {
                        uint4 ev = *(const uint4*)(csr2 + i);
                        int s0 = ev.x & 0xffff, s1 = ev.x >> 16;
                        int s2 = ev.y & 0xffff, s3 = ev.y >> 16;
                        int s4 = ev.z & 0xffff, s5 = ev.z >> 16;
                        int s6 = ev.w & 0xffff, s7 = ev.w >> 16;
                        uint4 u0 = *(const uint4*)(xp + (size_t)s0 * 16 + c0);
                        uint4 u1 = *(const uint4*)(xp + (size_t)s1 * 16 + c0);
                        uint4 u2 = *(const uint4*)(xp + (size_t)s2 * 16 + c0);
                        uint4 u3 = *(const uint4*)(xp + (size_t)s3 * 16 + c0);
                        uint4 u4 = *(const uint4*)(xp + (size_t)s4 * 16 + c0);
                        uint4 u5 = *(const uint4*)(xp + (size_t)s5 * 16 + c0);
                        uint4 u6 = *(const uint4*)(xp + (size_t)s6 * 16 + c0);
                        uint4 u7 = *(const uint4*)(xp + (size_t)s7 * 16 + c0);
                        bf8_add(acc, u0); bf8_add(acc, u1); bf8_add(acc, u2); bf8_add(acc, u3);
                        bf8_add(acc, u4); bf8_add(acc, u5); bf8_add(acc, u6); bf8_add(acc, u7);
                    }
                    float di = dinv[node];
                    #pragma unroll
                    for (int j = 0; j < 8; j++) acc[j] *= di;
                }
                #pragma unroll
                for (int j = 0; j < 8; j++) sm.m1.sH[nl * 16 + c0 + j] = acc[j];
            }
            __syncthreads();
            int c0 = (t & 15) * 4;
            int rbase = (t >> 4) * 4;
            float4 a0 = {0,0,0,0}, a1 = {0,0,0,0}, a2 = {0,0,0,0}, a3 = {0,0,0,0};
            for (int k = 0; k < FEAT; k++) {
                float4 w = *(const float4*)(sm.m1.sW + k * 64 + c0);
                float h0 = sm.m1.sH[(rbase + 0) * 16 + k];
                float h1v = sm.m1.sH[(rbase + 1) * 16 + k];
                float h2 = sm.m1.sH[(rbase + 2) * 16 + k];
                float h3 = sm.m1.sH[(rbase + 3) * 16 + k];
                a0.x += h0 * w.x; a0.y += h0 * w.y; a0.z += h0 * w.z; a0.w += h0 * w.w;
                a1.x += h1v * w.x; a1.y += h1v * w.y; a1.z += h1v * w.z; a1.w += h1v * w.w;
                a2.x += h2 * w.x; a2.y += h2 * w.y; a2.z += h2 * w.z; a2.w += h2 * w.w;
                a3.x += h3 * w.x; a3.y += h3 * w.y; a3.z += h3 * w.z; a3.w += h3 * w.w;
            }
            float4 bb = *(const float4*)(b1 + c0);
            float4 accs[4] = {a0, a1, a2, a3};
            for (int rr = 0; rr < 4; rr++) {
                int node = node0 + rbase + rr;
                if (node < N) {
                    float4 v = accs[rr];
                    v.x = fmaxf(v.x + bb.x, 0.f); v.y = fmaxf(v.y + bb.y, 0.f);
                    v.z = fmaxf(v.z + bb.z, 0.f); v.w = fmaxf(v.w + bb.w, 0.f);
                    *(float4*)(hf + (size_t)node * 64 + c0) = v;
                }
            }
            __syncthreads();
        }
    }
    gbar(bars + 5, NBLK);

    // ---- P6: mm64 (W2) -> hwb ----
    mm64_phase(sm, hf, W2, dinv, hwb, N, t, bid);
    gbar(bars + 6, NBLK);

    // ---- P7: gather (b2) -> hf ----
    gather64_phase<0>(sm, row_start, row_cntp, csr2, hwb, dinv, b2, hf, gsum, N, t, bid);
    gbar(bars + 7, NBLK);

    // ---- P8: mm64 (W3) -> hwb ----
    mm64_phase(sm, hf, W3, dinv, hwb, N, t, bid);
    gbar(bars + 8, NBLK);

    // ---- P9: gather (b3) -> hf, + gsum ----
    gather64_phase<1>(sm, row_start, row_cntp, csr2, hwb, dinv, b3, hf, gsum, N, t, bid);
    gbar(bars + 9, NBLK);

    // ---- P10: head ----
    if (bid < S) {
        int s = bid;
        int c = t & 63, jg = t >> 6;
        float acc = 0.0f;
        for (int j = jg; j < L; j += 4) {
            int node = sheet_idx[s * L + j];
            acc += hf[(size_t)node * 64 + c];
        }
        sm.fin.red[t] = acc;
        __syncthreads();
        if (t < 64) {
            sm.fin.semb[t] = (sm.fin.red[t] + sm.fin.red[t + 64] +
                              sm.fin.red[t + 128] + sm.fin.red[t + 192]) / (float)L;
            sm.fin.hq[64 + t] = gsum[t] / (float)N;
            float a = gb1[t];
            #pragma unroll
            for (int k = 0; k < FEAT; k++) a += sheet_feat[s * FEAT + k] * gW1[k * 64 + t];
            sm.fin.geoh[t] = fmaxf(a, 0.0f);
        }
        __syncthreads();
        if (t < 64) {
            float a = gb2[t];
            for (int k = 0; k < 64; k++) a += sm.fin.geoh[k] * gW2[k * 64 + t];
            sm.fin.geo[t] = a;
        }
        __syncthreads();
        if (t < 64) {
            float a = fb[t];
            for (int k = 0; k < 64; k++) a += sm.fin.semb[k] * fW[k * 64 + t];
            for (int k = 0; k < 64; k++) a += sm.fin.geo[k]  * fW[(64 + k) * 64 + t];
            sm.fin.hq[t] = fmaxf(a, 0.0f);
        }
        __syncthreads();
        if (t < 64) {
            float a = qb1[t];
            for (int k = 0; k < 128; k++) a += sm.fin.hq[k] * qW1[k * 64 + t];
            a = fmaxf(a, 0.0f);
            float q = a * qW2[t];
            for (int off = 32; off > 0; off >>= 1) q += __shfl_down(q, off, 64);
            if (t == 0) out[s] = q + qb2[0];
        }
    }
}

extern "C" void kernel_launch(void* const* d_in, const int* in_sizes, int n_in,
                              void* d_out, int out_size, void* d_ws, size_t ws_size,
                              hipStream_t stream) {
    const float* x          = (const float*)d_in[0];
    const int*   edge       = (const int*)d_in[1];
    const int*   sheet_idx  = (const int*)d_in[3];
    const float* sheet_feat = (const float*)d_in[4];
    const float* W1 = (const float*)d_in[5];  const float* b1 = (const float*)d_in[6];
    const float* W2 = (const float*)d_in[7];  const float* b2 = (const float*)d_in[8];
    const float* W3 = (const float*)d_in[9];  const float* b3 = (const float*)d_in[10];
    const float* gW1 = (const float*)d_in[11]; const float* gb1 = (const float*)d_in[12];
    const float* gW2 = (const float*)d_in[13]; const float* gb2 = (const float*)d_in[14];
    const float* fW  = (const float*)d_in[15]; const float* fb  = (const float*)d_in[16];
    const float* qW1 = (const float*)d_in[17]; const float* qb1 = (const float*)d_in[18];
    const float* qW2 = (const float*)d_in[19]; const float* qb2 = (const float*)d_in[20];
    float* out = (float*)d_out;

    int N = in_sizes[2];            // 50000
    int E = in_sizes[1] / 2;        // 800000
    int S = in_sizes[4] / FEAT;     // 256
    int L = in_sizes[3] / S;        // 128

    int nbuckets = (N + 255) / 256;     // 196
    int nchunks  = (E + 4095) / 4096;   // 196

    char* p = (char*)d_ws;
    unsigned* tmp  = (unsigned*)p;             p += (size_t)E * 4;
    u16* csr2      = (u16*)p;                  p += (size_t)nbuckets * MAXSEG * 2;
    float* hf      = (float*)p;                p += (size_t)N * 64 * 4;
    u16* hwb       = (u16*)p;                  p += (size_t)(N + 1) * 64 * 2;
    u16* xp        = (u16*)p;                  p += (size_t)(N + 1) * 16 * 2;
    int* row_start = (int*)p;                  p += (size_t)N * 4;
    int* row_cntp  = (int*)p;                  p += (size_t)N * 4;
    float* dinv    = (float*)p;                p += (size_t)N * 4;
    float* gsum    = (float*)p;                p += 64 * 4;
    int* bars      = (int*)p;                  p += 16 * 4;
    int* cnt2T     = (int*)p;                  p += (size_t)nbuckets * nchunks * 4;
    int* off2L     = (int*)p;                  p += (size_t)nbuckets * nchunks * 4;
    int* tot       = (int*)p;                  p += 256 * 4;
    int* base      = (int*)p;

    hipMemsetAsync(gsum, 0, 64 * 4 + 16 * 4, stream);   // gsum + barrier slots

    const int* src = edge;
    const int* dst = edge + E;

    fused<<<NBLK, NTHR, 0, stream>>>(
        x, src, dst, sheet_idx, sheet_feat,
        W1, b1, W2, b2, W3, b3, gW1, gb1, gW2, gb2, fW, fb, qW1, qb1, qW2, qb2,
        tmp, csr2, hf, hwb, xp, row_start, row_cntp, dinv, gsum, bars,
        cnt2T, off2L, tot, base, out, N, E, S, L, nbuckets, nchunks);
}

// Round 3
// 238.340 us; speedup vs baseline: 6.7751x; 6.7751x over previous
//
#include <hip/hip_runtime.h>

#define HID 64
#define FEAT 10
#define MAXSEG 8192        // fixed per-bucket segment (mean fill 4081, 64 sigma margin)

typedef unsigned short u16;

// ---------- helpers ----------
__device__ __forceinline__ u16 f2bf(float f) {            // fp32 -> bf16 RNE
    unsigned u = __float_as_uint(f);
    unsigned r = (u + 0x7fffu + ((u >> 16) & 1u)) >> 16;
    return (u16)r;
}
__device__ __forceinline__ void bf8_add(float* acc, uint4 u) {
    acc[0] += __uint_as_float(u.x << 16);
    acc[1] += __uint_as_float(u.x & 0xffff0000u);
    acc[2] += __uint_as_float(u.y << 16);
    acc[3] += __uint_as_float(u.y & 0xffff0000u);
    acc[4] += __uint_as_float(u.z << 16);
    acc[5] += __uint_as_float(u.z & 0xffff0000u);
    acc[6] += __uint_as_float(u.w << 16);
    acc[7] += __uint_as_float(u.w & 0xffff0000u);
}

// ================= CSR build (2 kernels) =================

// One pass over edges: LDS histogram -> global range reservation -> emit from registers.
// Bucket b owns tmp[b*MAXSEG .. b*MAXSEG+cnt). Also writes hwb/xp sentinel rows (block 0).
__global__ void bin_kernel(const int* __restrict__ src, const int* __restrict__ dst,
                           int* __restrict__ gcnt, unsigned* __restrict__ tmp,
                           u16* __restrict__ hwb, u16* __restrict__ xp,
                           int E, int N) {
    __shared__ int h[256];           // histogram, then current-slot cursors
    int t = threadIdx.x, c = blockIdx.x;
    if (t < 256) h[t] = 0;
    __syncthreads();
    int b0 = c * 4096;
    unsigned pk[4]; int bk[4];
    #pragma unroll
    for (int j = 0; j < 4; j++) {
        int e = b0 + t + j * 1024;
        if (e < E) {
            int s = src[e], d = dst[e];
            pk[j] = ((unsigned)(d & 255) << 16) | (unsigned)s;
            bk[j] = d >> 8;
            atomicAdd(&h[bk[j]], 1);
        } else bk[j] = -1;
    }
    __syncthreads();
    if (t < 256) {
        int v = h[t];
        int resv = v ? atomicAdd(&gcnt[t], v) : 0;
        h[t] = t * MAXSEG + resv;    // cursor = fixed bucket base + reserved offset
    }
    __syncthreads();
    #pragma unroll
    for (int j = 0; j < 4; j++) {
        if (bk[j] >= 0) {
            int slot = atomicAdd(&h[bk[j]], 1);
            tmp[slot] = pk[j];
        }
    }
    if (c == 0) {                    // sentinel rows (node N): zero
        if (t < 64)      hwb[(size_t)N * 64 + t] = 0;
        else if (t < 80) xp[(size_t)N * 16 + (t - 64)] = 0;
    }
}

// per-bucket node-sort into padded u16 CSR + row metadata + dinv + pad_x
__global__ void csr_build(const unsigned* __restrict__ tmp, const int* __restrict__ gcnt,
                          u16* __restrict__ csr2,
                          int* __restrict__ row_start, int* __restrict__ row_cntp,
                          float* __restrict__ dinv,
                          const float* __restrict__ x, u16* __restrict__ xp, int N) {
    __shared__ __align__(16) u16 staged[MAXSEG];
    __shared__ int cntL[256], padL[256], scanL[256], curL[256];
    __shared__ float sdinv[256];
    int b = blockIdx.x, t = threadIdx.x;          // 1024 threads
    if (t < 256) cntL[t] = 0;
    for (int i = t; i < MAXSEG; i += 1024) staged[i] = (u16)N;   // sentinel prefill
    __syncthreads();
    int segBase = b * MAXSEG, segLen = gcnt[b];
    for (int i = t; i < segLen; i += 1024)
        atomicAdd(&cntL[tmp[segBase + i] >> 16], 1);
    __syncthreads();
    if (t < 256) { padL[t] = (cntL[t] + 7) & ~7; scanL[t] = padL[t]; }
    __syncthreads();
    for (int off = 1; off < 256; off <<= 1) {
        int a = (t < 256) ? scanL[t] : 0;
        int s = (t >= off && t < 256) ? scanL[t - off] : 0;
        __syncthreads();
        if (t < 256) scanL[t] = a + s;
        __syncthreads();
    }
    if (t < 256) {
        int excl = scanL[t] - padL[t];
        curL[t] = excl;
        float dv = rsqrtf((float)cntL[t] + 1.0f);
        sdinv[t] = dv;
        int node = b * 256 + t;
        if (node < N) {
            row_start[node] = b * MAXSEG + excl;
            row_cntp[node]  = padL[t];
            dinv[node]      = dv;
        }
    }
    __syncthreads();
    for (int i = t; i < segLen; i += 1024) {
        unsigned e = tmp[segBase + i];
        int idx = atomicAdd(&curL[e >> 16], 1);
        staged[idx] = (u16)(e & 0xffffu);
    }
    // pad_x for this bucket's 256 nodes (independent of staged[])
    for (int i = t; i < 256 * 16; i += 1024) {
        int nlc = i >> 4, cch = i & 15;
        int node = b * 256 + nlc;
        if (node < N)
            xp[(size_t)node * 16 + cch] =
                (cch < FEAT) ? f2bf(sdinv[nlc] * x[(size_t)node * FEAT + cch]) : (u16)0;
    }
    __syncthreads();
    ((uint4*)(csr2 + (size_t)b * MAXSEG))[t] = ((const uint4*)staged)[t];
}

// ================= layer 1: gather_x + mm1 fused through LDS =================

__global__ void gxmm1(const int* __restrict__ row_start, const int* __restrict__ row_cntp,
                      const u16* __restrict__ csr2, const u16* __restrict__ xp,
                      const float* __restrict__ dinv,
                      const float* __restrict__ W1, const float* __restrict__ b1,
                      float* __restrict__ hf, int N) {
    __shared__ float sW[FEAT * 64];
    __shared__ float sH[64 * 16];
    int t = threadIdx.x;
    int node0 = blockIdx.x * 64;
    for (int i = t; i < FEAT * 64; i += 256) sW[i] = W1[i];
    if (t < 128) {
        int nl = t >> 1;
        int node = node0 + nl;
        int c0 = (t & 1) * 8;
        float acc[8] = {0.f,0.f,0.f,0.f,0.f,0.f,0.f,0.f};
        if (node < N) {
            uint4 sv = *(const uint4*)(xp + (size_t)node * 16 + c0);
            bf8_add(acc, sv);
            int i0 = row_start[node], iE = i0 + row_cntp[node];
            for (int i = i0; i < iE; i += 8) {
                uint4 ev = *(const uint4*)(csr2 + i);
                int s0 = ev.x & 0xffff, s1 = ev.x >> 16;
                int s2 = ev.y & 0xffff, s3 = ev.y >> 16;
                int s4 = ev.z & 0xffff, s5 = ev.z >> 16;
                int s6 = ev.w & 0xffff, s7 = ev.w >> 16;
                uint4 u0 = *(const uint4*)(xp + (size_t)s0 * 16 + c0);
                uint4 u1 = *(const uint4*)(xp + (size_t)s1 * 16 + c0);
                uint4 u2 = *(const uint4*)(xp + (size_t)s2 * 16 + c0);
                uint4 u3 = *(const uint4*)(xp + (size_t)s3 * 16 + c0);
                uint4 u4 = *(const uint4*)(xp + (size_t)s4 * 16 + c0);
                uint4 u5 = *(const uint4*)(xp + (size_t)s5 * 16 + c0);
                uint4 u6 = *(const uint4*)(xp + (size_t)s6 * 16 + c0);
                uint4 u7 = *(const uint4*)(xp + (size_t)s7 * 16 + c0);
                bf8_add(acc, u0); bf8_add(acc, u1); bf8_add(acc, u2); bf8_add(acc, u3);
                bf8_add(acc, u4); bf8_add(acc, u5); bf8_add(acc, u6); bf8_add(acc, u7);
            }
            float di = dinv[node];
            #pragma unroll
            for (int j = 0; j < 8; j++) acc[j] *= di;
        }
        #pragma unroll
        for (int j = 0; j < 8; j++) sH[nl * 16 + c0 + j] = acc[j];
    }
    __syncthreads();
    int c0 = (t & 15) * 4;
    int rbase = (t >> 4) * 4;
    float4 a0 = {0,0,0,0}, a1 = {0,0,0,0}, a2 = {0,0,0,0}, a3 = {0,0,0,0};
    for (int k = 0; k < FEAT; k++) {
        float4 w = *(const float4*)(sW + k * 64 + c0);
        float h0 = sH[(rbase + 0) * 16 + k];
        float h1v = sH[(rbase + 1) * 16 + k];
        float h2 = sH[(rbase + 2) * 16 + k];
        float h3 = sH[(rbase + 3) * 16 + k];
        a0.x += h0 * w.x; a0.y += h0 * w.y; a0.z += h0 * w.z; a0.w += h0 * w.w;
        a1.x += h1v * w.x; a1.y += h1v * w.y; a1.z += h1v * w.z; a1.w += h1v * w.w;
        a2.x += h2 * w.x; a2.y += h2 * w.y; a2.z += h2 * w.z; a2.w += h2 * w.w;
        a3.x += h3 * w.x; a3.y += h3 * w.y; a3.z += h3 * w.z; a3.w += h3 * w.w;
    }
    float4 bb = *(const float4*)(b1 + c0);
    float4 accs[4] = {a0, a1, a2, a3};
    for (int rr = 0; rr < 4; rr++) {
        int node = node0 + rbase + rr;
        if (node >= N) break;
        float4 v = accs[rr];
        v.x = fmaxf(v.x + bb.x, 0.f); v.y = fmaxf(v.y + bb.y, 0.f);
        v.z = fmaxf(v.z + bb.z, 0.f); v.w = fmaxf(v.w + bb.w, 0.f);
        *(float4*)(hf + (size_t)node * 64 + c0) = v;
    }
}

// ================= layers 2/3 =================

__global__ void gcn_matmul64(const float* __restrict__ h_in, const float* __restrict__ W,
                             const float* __restrict__ dinv, u16* __restrict__ hwb, int N) {
    __shared__ float sW[64 * 64];
    __shared__ float sH[64 * 65];
    int t = threadIdx.x;
    int node0 = blockIdx.x * 64;
    for (int i = t * 4; i < 4096; i += 1024)
        *(float4*)(sW + i) = *(const float4*)(W + i);
    for (int i = t; i < 4096; i += 256) {
        int r = i >> 6, k = i & 63;
        int node = node0 + r;
        sH[r * 65 + k] = (node < N) ? h_in[(size_t)node * 64 + k] : 0.0f;
    }
    __syncthreads();
    int c0 = (t & 15) * 4;
    int rbase = (t >> 4) * 4;
    float4 a0 = {0,0,0,0}, a1 = {0,0,0,0}, a2 = {0,0,0,0}, a3 = {0,0,0,0};
    for (int k = 0; k < 64; k++) {
        float4 w = *(const float4*)(sW + k * 64 + c0);
        float h0 = sH[(rbase + 0) * 65 + k];
        float h1v = sH[(rbase + 1) * 65 + k];
        float h2 = sH[(rbase + 2) * 65 + k];
        float h3 = sH[(rbase + 3) * 65 + k];
        a0.x += h0 * w.x; a0.y += h0 * w.y; a0.z += h0 * w.z; a0.w += h0 * w.w;
        a1.x += h1v * w.x; a1.y += h1v * w.y; a1.z += h1v * w.z; a1.w += h1v * w.w;
        a2.x += h2 * w.x; a2.y += h2 * w.y; a2.z += h2 * w.z; a2.w += h2 * w.w;
        a3.x += h3 * w.x; a3.y += h3 * w.y; a3.z += h3 * w.z; a3.w += h3 * w.w;
    }
    float4 accs[4] = {a0, a1, a2, a3};
    for (int rr = 0; rr < 4; rr++) {
        int node = node0 + rbase + rr;
        if (node >= N) break;
        float di = dinv[node];
        float4 v = accs[rr];
        ushort4 o;
        o.x = f2bf(v.x * di); o.y = f2bf(v.y * di);
        o.z = f2bf(v.z * di); o.w = f2bf(v.w * di);
        *(ushort4*)(hwb + (size_t)node * 64 + c0) = o;
    }
}

// 8 lanes per node, each lane owns 8 channels (16B) -> every neighbor access is one
// fully-utilized aligned 128B transaction.
__global__ void gather_bf(const int* __restrict__ row_start, const int* __restrict__ row_cntp,
                          const u16* __restrict__ csr2, const u16* __restrict__ hwb,
                          const float* __restrict__ dinv, const float* __restrict__ b,
                          float* __restrict__ out, float* __restrict__ gsum,
                          int N, int do_gsum) {
    int t = threadIdx.x;
    int nl = t >> 3;                       // 0..31 node slot in block
    int node = blockIdx.x * 32 + nl;
    int c0 = (t & 7) * 8;                  // first of this lane's 8 channels
    float acc[8] = {0.f,0.f,0.f,0.f,0.f,0.f,0.f,0.f};
    if (node < N) {
        uint4 sv = *(const uint4*)(hwb + (size_t)node * 64 + c0);
        bf8_add(acc, sv);
        int i0 = row_start[node], iE = i0 + row_cntp[node];
        for (int i = i0; i < iE; i += 8) {
            uint4 ev = *(const uint4*)(csr2 + i);
            int s0 = ev.x & 0xffff, s1 = ev.x >> 16;
            int s2 = ev.y & 0xffff, s3 = ev.y >> 16;
            int s4 = ev.z & 0xffff, s5 = ev.z >> 16;
            int s6 = ev.w & 0xffff, s7 = ev.w >> 16;
            uint4 u0 = *(const uint4*)(hwb + (size_t)s0 * 64 + c0);
            uint4 u1 = *(const uint4*)(hwb + (size_t)s1 * 64 + c0);
            uint4 u2 = *(const uint4*)(hwb + (size_t)s2 * 64 + c0);
            uint4 u3 = *(const uint4*)(hwb + (size_t)s3 * 64 + c0);
            uint4 u4 = *(const uint4*)(hwb + (size_t)s4 * 64 + c0);
            uint4 u5 = *(const uint4*)(hwb + (size_t)s5 * 64 + c0);
            uint4 u6 = *(const uint4*)(hwb + (size_t)s6 * 64 + c0);
            uint4 u7 = *(const uint4*)(hwb + (size_t)s7 * 64 + c0);
            bf8_add(acc, u0); bf8_add(acc, u1); bf8_add(acc, u2); bf8_add(acc, u3);
            bf8_add(acc, u4); bf8_add(acc, u5); bf8_add(acc, u6); bf8_add(acc, u7);
        }
        float di = dinv[node];
        const float4 bb0 = *(const float4*)(b + c0);
        const float4 bb1 = *(const float4*)(b + c0 + 4);
        float4 o0, o1;
        o0.x = fmaxf(acc[0]*di + bb0.x, 0.f); o0.y = fmaxf(acc[1]*di + bb0.y, 0.f);
        o0.z = fmaxf(acc[2]*di + bb0.z, 0.f); o0.w = fmaxf(acc[3]*di + bb0.w, 0.f);
        o1.x = fmaxf(acc[4]*di + bb1.x, 0.f); o1.y = fmaxf(acc[5]*di + bb1.y, 0.f);
        o1.z = fmaxf(acc[6]*di + bb1.z, 0.f); o1.w = fmaxf(acc[7]*di + bb1.w, 0.f);
        *(float4*)(out + (size_t)node * 64 + c0)     = o0;
        *(float4*)(out + (size_t)node * 64 + c0 + 4) = o1;
        acc[0]=o0.x; acc[1]=o0.y; acc[2]=o0.z; acc[3]=o0.w;
        acc[4]=o1.x; acc[5]=o1.y; acc[6]=o1.z; acc[7]=o1.w;
    }
    if (do_gsum) {
        __shared__ float red[32 * 64];
        #pragma unroll
        for (int j = 0; j < 8; j++) red[nl * 64 + c0 + j] = acc[j];
        __syncthreads();
        if (t < 64) {
            float s = 0.f;
            #pragma unroll 8
            for (int k = 0; k < 32; k++) s += red[k * 64 + t];
            atomicAdd(&gsum[t], s);
        }
    }
}

// ================= head =================

__global__ void final_kernel(const float* __restrict__ h3, const int* __restrict__ sheet_idx,
                             const float* __restrict__ sheet_feat, const float* __restrict__ g_sum,
                             const float* __restrict__ gW1, const float* __restrict__ gb1,
                             const float* __restrict__ gW2, const float* __restrict__ gb2,
                             const float* __restrict__ fW,  const float* __restrict__ fb,
                             const float* __restrict__ qW1, const float* __restrict__ qb1,
                             const float* __restrict__ qW2, const float* __restrict__ qb2,
                             float* __restrict__ out, int N, int L) {
    int s = blockIdx.x, t = threadIdx.x;
    __shared__ float red[256];
    __shared__ float semb[64];
    __shared__ float geoh[64];
    __shared__ float geo[64];
    __shared__ float hq[128];
    int c = t & 63, jg = t >> 6;
    float acc = 0.0f;
    for (int j = jg; j < L; j += 4) {
        int node = sheet_idx[s * L + j];
        acc += h3[(size_t)node * 64 + c];
    }
    red[t] = acc;
    __syncthreads();
    if (t < 64) {
        semb[t] = (red[t] + red[t + 64] + red[t + 128] + red[t + 192]) / (float)L;
        hq[64 + t] = g_sum[t] / (float)N;
        float a = gb1[t];
        #pragma unroll
        for (int k = 0; k < FEAT; k++) a += sheet_feat[s * FEAT + k] * gW1[k * 64 + t];
        geoh[t] = fmaxf(a, 0.0f);
    }
    __syncthreads();
    if (t < 64) {
        float a = gb2[t];
        for (int k = 0; k < 64; k++) a += geoh[k] * gW2[k * 64 + t];
        geo[t] = a;
    }
    __syncthreads();
    if (t < 64) {
        float a = fb[t];
        for (int k = 0; k < 64; k++) a += semb[k] * fW[k * 64 + t];
        for (int k = 0; k < 64; k++) a += geo[k]  * fW[(64 + k) * 64 + t];
        hq[t] = fmaxf(a, 0.0f);
    }
    __syncthreads();
    float q = 0.0f;
    if (t < 64) {
        float a = qb1[t];
        for (int k = 0; k < 128; k++) a += hq[k] * qW1[k * 64 + t];
        a = fmaxf(a, 0.0f);
        q = a * qW2[t];
        for (int off = 32; off > 0; off >>= 1) q += __shfl_down(q, off, 64);
        if (t == 0) out[s] = q + qb2[0];
    }
}

extern "C" void kernel_launch(void* const* d_in, const int* in_sizes, int n_in,
                              void* d_out, int out_size, void* d_ws, size_t ws_size,
                              hipStream_t stream) {
    const float* x          = (const float*)d_in[0];
    const int*   edge       = (const int*)d_in[1];
    const int*   sheet_idx  = (const int*)d_in[3];
    const float* sheet_feat = (const float*)d_in[4];
    const float* W1 = (const float*)d_in[5];  const float* b1 = (const float*)d_in[6];
    const float* W2 = (const float*)d_in[7];  const float* b2 = (const float*)d_in[8];
    const float* W3 = (const float*)d_in[9];  const float* b3 = (const float*)d_in[10];
    const float* gW1 = (const float*)d_in[11]; const float* gb1 = (const float*)d_in[12];
    const float* gW2 = (const float*)d_in[13]; const float* gb2 = (const float*)d_in[14];
    const float* fW  = (const float*)d_in[15]; const float* fb  = (const float*)d_in[16];
    const float* qW1 = (const float*)d_in[17]; const float* qb1 = (const float*)d_in[18];
    const float* qW2 = (const float*)d_in[19]; const float* qb2 = (const float*)d_in[20];
    float* out = (float*)d_out;

    int N = in_sizes[2];            // 50000
    int E = in_sizes[1] / 2;        // 800000
    int S = in_sizes[4] / FEAT;     // 256
    int L = in_sizes[3] / S;        // 128

    int nbuckets = (N + 255) / 256;     // 196 (u16 src requires N < 65535)
    int nchunks  = (E + 4095) / 4096;   // 196

    char* p = (char*)d_ws;
    unsigned* tmp  = (unsigned*)p;             p += (size_t)nbuckets * MAXSEG * 4;
    u16* csr2      = (u16*)p;                  p += (size_t)nbuckets * MAXSEG * 2;
    float* hf      = (float*)p;                p += (size_t)N * 64 * 4;
    u16* hwb       = (u16*)p;                  p += (size_t)(N + 1) * 64 * 2;   // [node][64] bf16
    u16* xp        = (u16*)p;                  p += (size_t)(N + 1) * 16 * 2;
    int* row_start = (int*)p;                  p += (size_t)N * 4;
    int* row_cntp  = (int*)p;                  p += (size_t)N * 4;
    float* dinv    = (float*)p;                p += (size_t)N * 4;
    int* gcnt      = (int*)p;                  p += 256 * 4;
    float* gsum    = (float*)p;                p += 64 * 4;

    hipMemsetAsync(gcnt, 0, 256 * 4 + 64 * 4, stream);   // gcnt + gsum (adjacent)

    const int* src = edge;
    const int* dst = edge + E;

    int gMM = (N + 63) / 64;            // 782
    int gGB = (N + 31) / 32;            // 1563

    bin_kernel<<<nchunks, 1024, 0, stream>>>(src, dst, gcnt, tmp, hwb, xp, E, N);
    csr_build<<<nbuckets, 1024, 0, stream>>>(tmp, gcnt, csr2, row_start, row_cntp, dinv, x, xp, N);

    gxmm1<<<gMM, 256, 0, stream>>>(row_start, row_cntp, csr2, xp, dinv, W1, b1, hf, N);

    gcn_matmul64<<<gMM, 256, 0, stream>>>(hf, W2, dinv, hwb, N);
    gather_bf<<<gGB, 256, 0, stream>>>(row_start, row_cntp, csr2, hwb, dinv, b2, hf, gsum, N, 0);

    gcn_matmul64<<<gMM, 256, 0, stream>>>(hf, W3, dinv, hwb, N);
    gather_bf<<<gGB, 256, 0, stream>>>(row_start, row_cntp, csr2, hwb, dinv, b3, hf, gsum, N, 1);

    final_kernel<<<S, 256, 0, stream>>>(hf, sheet_idx, sheet_feat, gsum,
                                        gW1, gb1, gW2, gb2, fW, fb,
                                        qW1, qb1, qW2, qb2, out, N, L);
}